// Round 2
// baseline (1361.223 us; speedup 1.0000x reference)
//
#include <hip/hip_runtime.h>
#include <math.h>

#define NROWS 16384
#define DDIM  1024
#define HIDD  4096
// IN_DIM = 4097 handled as K=4096 + last-row epilogue term

typedef __bf16 bf16;
typedef bf16 bf16x8 __attribute__((ext_vector_type(8)));
typedef bf16 bf16x4 __attribute__((ext_vector_type(4)));
typedef float f32x4 __attribute__((ext_vector_type(4)));

__device__ __forceinline__ float gelu_erf(float x) {
  return 0.5f * x * (1.0f + erff(x * 0.70710678118654752f));
}

__device__ __forceinline__ void gld16(const bf16* g, bf16* l) {
  __builtin_amdgcn_global_load_lds(
      (const __attribute__((address_space(1))) void*)g,
      (__attribute__((address_space(3))) void*)l, 16, 0, 0);
}

// ---------------- elementwise cast fp32 -> bf16 (vector4) ----------------
__global__ __launch_bounds__(256) void cast_bf16_k(const float* __restrict__ in,
                                                   bf16* __restrict__ out) {
  size_t i = (size_t)blockIdx.x * blockDim.x + threadIdx.x;
  float4 v = ((const float4*)in)[i];
  bf16x4 o = {(bf16)v.x, (bf16)v.y, (bf16)v.z, (bf16)v.w};
  ((bf16x4*)out)[i] = o;
}

// ---------------- tiled transpose + cast: in[R][C] fp32 -> out[C][R] bf16 ----
__global__ __launch_bounds__(256) void transpose_cast_k(const float* __restrict__ in,
                                                        bf16* __restrict__ out,
                                                        int R, int C) {
  __shared__ float tile[32][33];
  int bx = blockIdx.x * 32, by = blockIdx.y * 32;
  int tx = threadIdx.x, ty = threadIdx.y;
  #pragma unroll
  for (int i = ty; i < 32; i += 8)
    tile[i][tx] = in[(size_t)(by + i) * C + bx + tx];
  __syncthreads();
  #pragma unroll
  for (int i = ty; i < 32; i += 8)
    out[(size_t)(bx + i) * R + by + tx] = (bf16)tile[tx][i];
}

// ---------------- fused row op: had/diff/s + LayerNorm -> x_bf16, s_ln -------
__global__ __launch_bounds__(256) void rowfuse_k(
    const float* __restrict__ zA, const float* __restrict__ zB,
    const bf16* __restrict__ t, const float* __restrict__ lng,
    const float* __restrict__ lnb, bf16* __restrict__ x,
    float* __restrict__ s_ln) {
  int row = blockIdx.x, tid = threadIdx.x;
  float4 a4 = ((const float4*)(zA + (size_t)row * DDIM))[tid];
  float4 b4 = ((const float4*)(zB + (size_t)row * DDIM))[tid];
  bf16x4 t4 = ((const bf16x4*)(t + (size_t)row * DDIM))[tid];
  float av[4] = {a4.x, a4.y, a4.z, a4.w};
  float bv[4] = {b4.x, b4.y, b4.z, b4.w};
  float hv[4], dv[4];
  float s1 = 0.f, s2 = 0.f, sd = 0.f;
  #pragma unroll
  for (int j = 0; j < 4; j++) {
    hv[j] = av[j] * bv[j];
    dv[j] = fabsf(av[j] - bv[j]);
    s1 += av[j] + bv[j] + hv[j] + dv[j];
    s2 += av[j]*av[j] + bv[j]*bv[j] + hv[j]*hv[j] + dv[j]*dv[j];
    sd += (float)t4[j] * bv[j];
  }
  #pragma unroll
  for (int off = 32; off > 0; off >>= 1) {
    s1 += __shfl_xor(s1, off, 64);
    s2 += __shfl_xor(s2, off, 64);
    sd += __shfl_xor(sd, off, 64);
  }
  __shared__ float red[3][4];
  int wave = tid >> 6;
  if ((tid & 63) == 0) { red[0][wave] = s1; red[1][wave] = s2; red[2][wave] = sd; }
  __syncthreads();
  s1 = red[0][0] + red[0][1] + red[0][2] + red[0][3];
  s2 = red[1][0] + red[1][1] + red[1][2] + red[1][3];
  float s = red[2][0] + red[2][1] + red[2][2] + red[2][3];
  const float inv = 1.0f / 4097.0f;
  float mu = (s1 + s) * inv;
  float var = (s2 + s * s) * inv - mu * mu;
  float rs = rsqrtf(var + 1e-5f);
  bf16* xr = x + (size_t)row * 4096;
  #define WRITE_SEG(si, vals)                                            \
  {                                                                      \
    float4 gg = ((const float4*)lng)[(si)*256 + tid];                    \
    float4 bb = ((const float4*)lnb)[(si)*256 + tid];                    \
    const float* gp = (const float*)&gg;                                 \
    const float* bp = (const float*)&bb;                                 \
    bf16x4 o;                                                            \
    _Pragma("unroll") for (int j = 0; j < 4; j++)                        \
        o[j] = (bf16)((vals[j] - mu) * rs * gp[j] + bp[j]);              \
    ((bf16x4*)xr)[(si)*256 + tid] = o;                                   \
  }
  WRITE_SEG(0, av)
  WRITE_SEG(1, bv)
  WRITE_SEG(2, hv)
  WRITE_SEG(3, dv)
  #undef WRITE_SEG
  if (tid == 0) s_ln[row] = (s - mu) * rs * lng[4096] + lnb[4096];
}

// ---------------- bf16 MFMA GEMM: C = A[M,K] * B^T[N,K] (both K-contig) -----
// EPI 0: store bf16 (t = zA@bilinear)
// EPI 1: v += b1[col] + s_ln[row]*w1last[col]; gelu; store bf16 (h)
// EPI 2: v += b2[col]; gelu; store fp32 (out)
template <int EPI>
__global__ __launch_bounds__(256) void gemm_bt_k(
    const bf16* __restrict__ A, const bf16* __restrict__ B, int K, int Nout,
    void* __restrict__ Cout, const float* __restrict__ bias,
    const float* __restrict__ srow, const float* __restrict__ wlast) {
  __shared__ alignas(16) bf16 As[128 * 64];
  __shared__ alignas(16) bf16 Bs[128 * 64];
  const int tid = threadIdx.x;
  const int wave = tid >> 6, lane = tid & 63;
  const int wm = wave >> 1, wn = wave & 1;
  const int lrow = lane & 15, quad = lane >> 4;
  const size_t rowA0 = (size_t)blockIdx.y * 128;
  const size_t rowB0 = (size_t)blockIdx.x * 128;

  f32x4 acc[4][4] = {};

  const bf16* gA = A + (rowA0 + (tid >> 3)) * (size_t)K + (tid & 7) * 8;
  const bf16* gB = B + (rowB0 + (tid >> 3)) * (size_t)K + (tid & 7) * 8;

  for (int kb = 0; kb < K; kb += 64) {
    const bf16* pa = gA + kb;
    const bf16* pb = gB + kb;
    #pragma unroll
    for (int it = 0; it < 4; it++) {
      gld16(pa + (size_t)it * 32 * K, As + it * 2048 + wave * 512);
      gld16(pb + (size_t)it * 32 * K, Bs + it * 2048 + wave * 512);
    }
    __syncthreads();
    #pragma unroll
    for (int kk = 0; kk < 2; kk++) {
      bf16x8 af[4], bfr[4];
      #pragma unroll
      for (int mi = 0; mi < 4; mi++)
        af[mi] = *(const bf16x8*)(As + (wm * 64 + mi * 16 + lrow) * 64 + kk * 32 + quad * 8);
      #pragma unroll
      for (int ni = 0; ni < 4; ni++)
        bfr[ni] = *(const bf16x8*)(Bs + (wn * 64 + ni * 16 + lrow) * 64 + kk * 32 + quad * 8);
      #pragma unroll
      for (int mi = 0; mi < 4; mi++)
        #pragma unroll
        for (int ni = 0; ni < 4; ni++)
          acc[mi][ni] = __builtin_amdgcn_mfma_f32_16x16x32_bf16(af[mi], bfr[ni], acc[mi][ni], 0, 0, 0);
    }
    __syncthreads();
  }

  const size_t ldc = (size_t)Nout;
  #pragma unroll
  for (int mi = 0; mi < 4; mi++) {
    size_t row = rowA0 + wm * 64 + mi * 16 + quad * 4;
    float srv[4];
    if (EPI == 1) {
      #pragma unroll
      for (int r = 0; r < 4; r++) srv[r] = srow[row + r];
    }
    #pragma unroll
    for (int ni = 0; ni < 4; ni++) {
      size_t col = rowB0 + wn * 64 + ni * 16 + lrow;
      float bvv = (EPI != 0) ? bias[col] : 0.0f;
      float wl = (EPI == 1) ? wlast[col] : 0.0f;
      #pragma unroll
      for (int r = 0; r < 4; r++) {
        float v = acc[mi][ni][r];
        if (EPI == 1) v += bvv + srv[r] * wl;
        if (EPI == 2) v += bvv;
        if (EPI != 0) v = gelu_erf(v);
        size_t idx = (row + r) * ldc + col;
        if (EPI == 2) ((float*)Cout)[idx] = v;
        else ((bf16*)Cout)[idx] = (bf16)v;
      }
    }
  }
}

extern "C" void kernel_launch(void* const* d_in, const int* in_sizes, int n_in,
                              void* d_out, int out_size, void* d_ws, size_t ws_size,
                              hipStream_t stream) {
  const float* zA  = (const float*)d_in[0];
  const float* zB  = (const float*)d_in[1];
  const float* bil = (const float*)d_in[2];
  const float* lng = (const float*)d_in[3];
  const float* lnb = (const float*)d_in[4];
  const float* W1  = (const float*)d_in[5];
  const float* b1  = (const float*)d_in[6];
  const float* W2  = (const float*)d_in[7];
  const float* b2  = (const float*)d_in[8];
  float* out = (float*)d_out;

  // ---- workspace layout (adaptive row-chunking) ----
  // persistent: bilT (2 MiB) | W1T (32 MiB) | W2T (8 MiB)
  // per chunk C rows:
  //   region1 (8192*C B): [zA_bf (2048C) | t_bf (2048C)] then reused as h (8192C)
  //   region2 (8192*C B): x
  //   s_ln: 4*C
  char* ws = (char*)d_ws;
  const size_t SZ_BILT = (size_t)DDIM * DDIM * 2;        //  2 MiB
  const size_t SZ_W1T  = (size_t)4096 * 4096 * 2;        // 32 MiB
  const size_t SZ_W2T  = (size_t)DDIM * HIDD * 2;        //  8 MiB
  const size_t PERSIST = SZ_BILT + SZ_W1T + SZ_W2T;      // 42 MiB

  int C = 0;
  for (int cand = NROWS; cand >= 512; cand >>= 1) {
    size_t need = PERSIST + (size_t)16384 * cand + (size_t)4 * cand + 1024;
    if (need <= ws_size) { C = cand; break; }
  }
  if (C == 0) return;  // workspace hopelessly small — leave poison (fail loudly)

  bf16* bilT = (bf16*)ws;
  bf16* W1T  = (bf16*)(ws + SZ_BILT);
  bf16* W2T  = (bf16*)(ws + SZ_BILT + SZ_W1T);
  char* dyn  = ws + PERSIST;
  bf16*  r1    = (bf16*)dyn;                              // region1: zA_bf|t_bf -> h
  bf16*  zA_bf = r1;                                      // [C,1024] bf16
  bf16*  t_bf  = r1 + (size_t)C * 1024;                   // [C,1024] bf16
  bf16*  h_bf  = r1;                                      // [C,4096] bf16 (overlays after rowfuse)
  bf16*  x_bf  = (bf16*)(dyn + (size_t)8192 * C);         // [C,4096] bf16
  float* s_ln  = (float*)(dyn + (size_t)16384 * C);       // [C] fp32

  dim3 tb(32, 8);
  transpose_cast_k<<<dim3(DDIM / 32, DDIM / 32), tb, 0, stream>>>(bil, bilT, DDIM, DDIM);
  transpose_cast_k<<<dim3(HIDD / 32, 4096 / 32), tb, 0, stream>>>(W1, W1T, 4096, HIDD);
  transpose_cast_k<<<dim3(DDIM / 32, HIDD / 32), tb, 0, stream>>>(W2, W2T, HIDD, DDIM);

  for (int r0 = 0; r0 < NROWS; r0 += C) {
    const float* zAc = zA + (size_t)r0 * DDIM;
    const float* zBc = zB + (size_t)r0 * DDIM;

    // cast zA chunk -> bf16
    cast_bf16_k<<<(C * DDIM / 4) / 256, 256, 0, stream>>>(zAc, zA_bf);

    // t = zA @ bilinear   [C, DDIM]
    gemm_bt_k<0><<<dim3(DDIM / 128, C / 128), 256, 0, stream>>>(
        zA_bf, bilT, DDIM, DDIM, t_bf, nullptr, nullptr, nullptr);

    // had/diff/s + LayerNorm -> x_bf, s_ln
    rowfuse_k<<<C, 256, 0, stream>>>(zAc, zBc, t_bf, lng, lnb, x_bf, s_ln);

    // h = gelu(x @ W1 + b1 + s_ln*W1_last)   [C, HIDD]  (h overlays zA_bf/t_bf)
    gemm_bt_k<1><<<dim3(HIDD / 128, C / 128), 256, 0, stream>>>(
        x_bf, W1T, 4096, HIDD, h_bf, b1, s_ln, W1 + (size_t)4096 * HIDD);

    // out = gelu(h @ W2 + b2)   [C, DDIM]
    gemm_bt_k<2><<<dim3(DDIM / 128, C / 128), 256, 0, stream>>>(
        h_bf, W2T, 4096, DDIM, out + (size_t)r0 * DDIM, b2, nullptr, nullptr);
  }
}

// Round 3
// 1127.710 us; speedup vs baseline: 1.2071x; 1.2071x over previous
//
#include <hip/hip_runtime.h>
#include <math.h>

#define NROWS 16384
#define DDIM  1024
#define HIDD  4096
// IN_DIM = 4097 handled as K=4096 + last-row epilogue term

typedef __bf16 bf16;
typedef bf16 bf16x8 __attribute__((ext_vector_type(8)));
typedef bf16 bf16x4 __attribute__((ext_vector_type(4)));
typedef float f32x4 __attribute__((ext_vector_type(4)));

__device__ __forceinline__ float gelu_erf(float x) {
  return 0.5f * x * (1.0f + erff(x * 0.70710678118654752f));
}

__device__ __forceinline__ void gld16(const bf16* g, bf16* l) {
  __builtin_amdgcn_global_load_lds(
      (const __attribute__((address_space(1))) void*)g,
      (__attribute__((address_space(3))) void*)l, 16, 0, 0);
}

// ---------------- elementwise cast fp32 -> bf16 (vector4) ----------------
__global__ __launch_bounds__(256) void cast_bf16_k(const float* __restrict__ in,
                                                   bf16* __restrict__ out) {
  size_t i = (size_t)blockIdx.x * blockDim.x + threadIdx.x;
  float4 v = ((const float4*)in)[i];
  bf16x4 o = {(bf16)v.x, (bf16)v.y, (bf16)v.z, (bf16)v.w};
  ((bf16x4*)out)[i] = o;
}

// ---------------- tiled transpose + cast: in[R][C] fp32 -> out[C][R] bf16 ----
__global__ __launch_bounds__(256) void transpose_cast_k(const float* __restrict__ in,
                                                        bf16* __restrict__ out,
                                                        int R, int C) {
  __shared__ float tile[32][33];
  int bx = blockIdx.x * 32, by = blockIdx.y * 32;
  int tx = threadIdx.x, ty = threadIdx.y;
  #pragma unroll
  for (int i = ty; i < 32; i += 8)
    tile[i][tx] = in[(size_t)(by + i) * C + bx + tx];
  __syncthreads();
  #pragma unroll
  for (int i = ty; i < 32; i += 8)
    out[(size_t)(bx + i) * R + by + tx] = (bf16)tile[tx][i];
}

// ---------------- fused row op: had/diff/s + LayerNorm -> x_bf16, s_ln -------
__global__ __launch_bounds__(256) void rowfuse_k(
    const float* __restrict__ zA, const float* __restrict__ zB,
    const bf16* __restrict__ t, const float* __restrict__ lng,
    const float* __restrict__ lnb, bf16* __restrict__ x,
    float* __restrict__ s_ln) {
  int row = blockIdx.x, tid = threadIdx.x;
  float4 a4 = ((const float4*)(zA + (size_t)row * DDIM))[tid];
  float4 b4 = ((const float4*)(zB + (size_t)row * DDIM))[tid];
  bf16x4 t4 = ((const bf16x4*)(t + (size_t)row * DDIM))[tid];
  float av[4] = {a4.x, a4.y, a4.z, a4.w};
  float bv[4] = {b4.x, b4.y, b4.z, b4.w};
  float hv[4], dv[4];
  float s1 = 0.f, s2 = 0.f, sd = 0.f;
  #pragma unroll
  for (int j = 0; j < 4; j++) {
    hv[j] = av[j] * bv[j];
    dv[j] = fabsf(av[j] - bv[j]);
    s1 += av[j] + bv[j] + hv[j] + dv[j];
    s2 += av[j]*av[j] + bv[j]*bv[j] + hv[j]*hv[j] + dv[j]*dv[j];
    sd += (float)t4[j] * bv[j];
  }
  #pragma unroll
  for (int off = 32; off > 0; off >>= 1) {
    s1 += __shfl_xor(s1, off, 64);
    s2 += __shfl_xor(s2, off, 64);
    sd += __shfl_xor(sd, off, 64);
  }
  __shared__ float red[3][4];
  int wave = tid >> 6;
  if ((tid & 63) == 0) { red[0][wave] = s1; red[1][wave] = s2; red[2][wave] = sd; }
  __syncthreads();
  s1 = red[0][0] + red[0][1] + red[0][2] + red[0][3];
  s2 = red[1][0] + red[1][1] + red[1][2] + red[1][3];
  float s = red[2][0] + red[2][1] + red[2][2] + red[2][3];
  const float inv = 1.0f / 4097.0f;
  float mu = (s1 + s) * inv;
  float var = (s2 + s * s) * inv - mu * mu;
  float rs = rsqrtf(var + 1e-5f);
  bf16* xr = x + (size_t)row * 4096;
  #define WRITE_SEG(si, vals)                                            \
  {                                                                      \
    float4 gg = ((const float4*)lng)[(si)*256 + tid];                    \
    float4 bb = ((const float4*)lnb)[(si)*256 + tid];                    \
    const float* gp = (const float*)&gg;                                 \
    const float* bp = (const float*)&bb;                                 \
    bf16x4 o;                                                            \
    _Pragma("unroll") for (int j = 0; j < 4; j++)                        \
        o[j] = (bf16)((vals[j] - mu) * rs * gp[j] + bp[j]);              \
    ((bf16x4*)xr)[(si)*256 + tid] = o;                                   \
  }
  WRITE_SEG(0, av)
  WRITE_SEG(1, bv)
  WRITE_SEG(2, hv)
  WRITE_SEG(3, dv)
  #undef WRITE_SEG
  if (tid == 0) s_ln[row] = (s - mu) * rs * lng[4096] + lnb[4096];
}

// ---------------- bf16 MFMA GEMM: C = A[M,K] * B^T[N,K] (both K-contig) -----
// LDS layout uses an XOR-8 chunk swizzle: LDS chunk c (16B) of row r holds
// global chunk c ^ (r&7). Staging permutes the lane->chunk assignment (stays
// within global_load_lds's lane-contiguous LDS constraint and keeps the
// 128B-segment coalescing); fragment reads XOR the chunk index. This balances
// ds_read_b128 across all 32 banks (8 dword-accesses/bank/wave, 0 conflicts)
// vs the unswizzled layout's 16-on-half-the-banks (2x LDS time).
// EPI 0: store bf16 (t = zA@bilinear)
// EPI 1: v += b1[col] + s_ln[row]*w1last[col]; gelu; store bf16 (h)
// EPI 2: v += b2[col]; gelu; store fp32 (out)
template <int EPI>
__global__ __launch_bounds__(256) void gemm_bt_k(
    const bf16* __restrict__ A, const bf16* __restrict__ B, int K, int Nout,
    void* __restrict__ Cout, const float* __restrict__ bias,
    const float* __restrict__ srow, const float* __restrict__ wlast) {
  __shared__ alignas(16) bf16 As[128 * 64];
  __shared__ alignas(16) bf16 Bs[128 * 64];
  const int tid = threadIdx.x;
  const int wave = tid >> 6, lane = tid & 63;
  const int wm = wave >> 1, wn = wave & 1;
  const int lrow = lane & 15, quad = lane >> 4;
  const size_t rowA0 = (size_t)blockIdx.y * 128;
  const size_t rowB0 = (size_t)blockIdx.x * 128;

  f32x4 acc[4][4] = {};

  // swizzled lane->global-chunk assignment for staging
  const int lchunk = (tid & 7) ^ ((tid >> 3) & 7);
  const bf16* gA = A + (rowA0 + (tid >> 3)) * (size_t)K + lchunk * 8;
  const bf16* gB = B + (rowB0 + (tid >> 3)) * (size_t)K + lchunk * 8;

  for (int kb = 0; kb < K; kb += 64) {
    const bf16* pa = gA + kb;
    const bf16* pb = gB + kb;
    #pragma unroll
    for (int it = 0; it < 4; it++) {
      gld16(pa + (size_t)it * 32 * K, As + it * 2048 + wave * 512);
      gld16(pb + (size_t)it * 32 * K, Bs + it * 2048 + wave * 512);
    }
    __syncthreads();
    #pragma unroll
    for (int kk = 0; kk < 2; kk++) {
      const int cla = ((kk * 4 + quad) ^ (lrow & 7)) * 8;  // swizzled chunk offset
      bf16x8 af[4], bfr[4];
      #pragma unroll
      for (int mi = 0; mi < 4; mi++)
        af[mi] = *(const bf16x8*)(As + (wm * 64 + mi * 16 + lrow) * 64 + cla);
      #pragma unroll
      for (int ni = 0; ni < 4; ni++)
        bfr[ni] = *(const bf16x8*)(Bs + (wn * 64 + ni * 16 + lrow) * 64 + cla);
      #pragma unroll
      for (int mi = 0; mi < 4; mi++)
        #pragma unroll
        for (int ni = 0; ni < 4; ni++)
          acc[mi][ni] = __builtin_amdgcn_mfma_f32_16x16x32_bf16(af[mi], bfr[ni], acc[mi][ni], 0, 0, 0);
    }
    __syncthreads();
  }

  const size_t ldc = (size_t)Nout;
  #pragma unroll
  for (int mi = 0; mi < 4; mi++) {
    size_t row = rowA0 + wm * 64 + mi * 16 + quad * 4;
    float srv[4];
    if (EPI == 1) {
      #pragma unroll
      for (int r = 0; r < 4; r++) srv[r] = srow[row + r];
    }
    #pragma unroll
    for (int ni = 0; ni < 4; ni++) {
      size_t col = rowB0 + wn * 64 + ni * 16 + lrow;
      float bvv = (EPI != 0) ? bias[col] : 0.0f;
      float wl = (EPI == 1) ? wlast[col] : 0.0f;
      #pragma unroll
      for (int r = 0; r < 4; r++) {
        float v = acc[mi][ni][r];
        if (EPI == 1) v += bvv + srv[r] * wl;
        if (EPI == 2) v += bvv;
        if (EPI != 0) v = gelu_erf(v);
        size_t idx = (row + r) * ldc + col;
        if (EPI == 2) ((float*)Cout)[idx] = v;
        else ((bf16*)Cout)[idx] = (bf16)v;
      }
    }
  }
}

extern "C" void kernel_launch(void* const* d_in, const int* in_sizes, int n_in,
                              void* d_out, int out_size, void* d_ws, size_t ws_size,
                              hipStream_t stream) {
  const float* zA  = (const float*)d_in[0];
  const float* zB  = (const float*)d_in[1];
  const float* bil = (const float*)d_in[2];
  const float* lng = (const float*)d_in[3];
  const float* lnb = (const float*)d_in[4];
  const float* W1  = (const float*)d_in[5];
  const float* b1  = (const float*)d_in[6];
  const float* W2  = (const float*)d_in[7];
  const float* b2  = (const float*)d_in[8];
  float* out = (float*)d_out;

  // ---- workspace layout (adaptive row-chunking) ----
  char* ws = (char*)d_ws;
  const size_t SZ_BILT = (size_t)DDIM * DDIM * 2;        //  2 MiB
  const size_t SZ_W1T  = (size_t)4096 * 4096 * 2;        // 32 MiB
  const size_t SZ_W2T  = (size_t)DDIM * HIDD * 2;        //  8 MiB
  const size_t PERSIST = SZ_BILT + SZ_W1T + SZ_W2T;      // 42 MiB

  int C = 0;
  for (int cand = NROWS; cand >= 512; cand >>= 1) {
    size_t need = PERSIST + (size_t)16384 * cand + (size_t)4 * cand + 1024;
    if (need <= ws_size) { C = cand; break; }
  }
  if (C == 0) return;  // workspace hopelessly small — leave poison (fail loudly)

  bf16* bilT = (bf16*)ws;
  bf16* W1T  = (bf16*)(ws + SZ_BILT);
  bf16* W2T  = (bf16*)(ws + SZ_BILT + SZ_W1T);
  char* dyn  = ws + PERSIST;
  bf16*  r1    = (bf16*)dyn;                              // region1: zA_bf|t_bf -> h
  bf16*  zA_bf = r1;                                      // [C,1024] bf16
  bf16*  t_bf  = r1 + (size_t)C * 1024;                   // [C,1024] bf16
  bf16*  h_bf  = r1;                                      // [C,4096] bf16 (overlays after rowfuse)
  bf16*  x_bf  = (bf16*)(dyn + (size_t)8192 * C);         // [C,4096] bf16
  float* s_ln  = (float*)(dyn + (size_t)16384 * C);       // [C] fp32

  dim3 tb(32, 8);
  transpose_cast_k<<<dim3(DDIM / 32, DDIM / 32), tb, 0, stream>>>(bil, bilT, DDIM, DDIM);
  transpose_cast_k<<<dim3(HIDD / 32, 4096 / 32), tb, 0, stream>>>(W1, W1T, 4096, HIDD);
  transpose_cast_k<<<dim3(DDIM / 32, HIDD / 32), tb, 0, stream>>>(W2, W2T, HIDD, DDIM);

  for (int r0 = 0; r0 < NROWS; r0 += C) {
    const float* zAc = zA + (size_t)r0 * DDIM;
    const float* zBc = zB + (size_t)r0 * DDIM;

    // cast zA chunk -> bf16
    cast_bf16_k<<<(C * DDIM / 4) / 256, 256, 0, stream>>>(zAc, zA_bf);

    // t = zA @ bilinear   [C, DDIM]
    gemm_bt_k<0><<<dim3(DDIM / 128, C / 128), 256, 0, stream>>>(
        zA_bf, bilT, DDIM, DDIM, t_bf, nullptr, nullptr, nullptr);

    // had/diff/s + LayerNorm -> x_bf, s_ln
    rowfuse_k<<<C, 256, 0, stream>>>(zAc, zBc, t_bf, lng, lnb, x_bf, s_ln);

    // h = gelu(x @ W1 + b1 + s_ln*W1_last)   [C, HIDD]  (h overlays zA_bf/t_bf)
    gemm_bt_k<1><<<dim3(HIDD / 128, C / 128), 256, 0, stream>>>(
        x_bf, W1T, 4096, HIDD, h_bf, b1, s_ln, W1 + (size_t)4096 * HIDD);

    // out = gelu(h @ W2 + b2)   [C, DDIM]
    gemm_bt_k<2><<<dim3(DDIM / 128, C / 128), 256, 0, stream>>>(
        h_bf, W2T, 4096, DDIM, out + (size_t)r0 * DDIM, b2, nullptr, nullptr);
  }
}